// Round 8
// baseline (322.832 us; speedup 1.0000x reference)
//
#include <hip/hip_runtime.h>

#define N_NODES 50000
#define N_EDGES 800000
#define NUM_GRAPHS 256
#define HID 128
#define IN_DIM 64
#define BN_EPS 1e-5f
#define SPREAD 16
#define NB 196            // buckets: dst>>8
#define BUCKET 256        // nodes per bucket
#define SCHUNK 4096       // edges per scatter block
#define NCHUNK 196        // ceil(N_EDGES/SCHUNK)
#define PX_BLKS 1563      // ceil(N_NODES*8/256)
#define W0_BLKS 8         // 8*4*64/256
#define W1_BLKS 16        // 8*8*64/256

typedef __attribute__((ext_vector_type(8))) short bf16x8;
typedef __attribute__((ext_vector_type(4))) float f32x4;

// ---- bf16 helpers ----
__device__ __forceinline__ float bf2f(unsigned short u){ union{unsigned i;float f;}c; c.i=((unsigned)u)<<16; return c.f; }
__device__ __forceinline__ float bflo(unsigned w){ union{unsigned i;float f;}c; c.i=w<<16; return c.f; }
__device__ __forceinline__ float bfhi(unsigned w){ union{unsigned i;float f;}c; c.i=w&0xFFFF0000u; return c.f; }
__device__ __forceinline__ unsigned short f2bf(float f){ union{float f;unsigned i;}c; c.f=f; unsigned r=c.i+0x7FFF+((c.i>>16)&1); return (unsigned short)(r>>16); }
__device__ __forceinline__ unsigned fpack(float a, float b){
  union{float f;unsigned i;}ca,cb; ca.f=a; cb.f=b;
  unsigned ra=((ca.i+0x7FFF+((ca.i>>16)&1))>>16)&0xFFFFu;
  unsigned rb=(cb.i+0x7FFF+((cb.i>>16)&1))&0xFFFF0000u;
  return ra|rb;
}
__device__ __forceinline__ void acc8(float* a, uint4 u){
  a[0]+=bflo(u.x); a[1]+=bfhi(u.x); a[2]+=bflo(u.y); a[3]+=bfhi(u.y);
  a[4]+=bflo(u.z); a[5]+=bfhi(u.z); a[6]+=bflo(u.w); a[7]+=bfhi(u.w);
}

// ---------------- bucket histogram ----------------
__global__ __launch_bounds__(256) void k_hist(const int* __restrict__ dst, int* __restrict__ bcount){
  __shared__ int h[NB];
  int t = threadIdx.x;
  for(int i=t;i<NB;i+=256) h[i]=0;
  __syncthreads();
  int base = blockIdx.x*SCHUNK;
  int n = min(SCHUNK, N_EDGES-base);
  for(int v=t; v<n; v+=256) atomicAdd(&h[dst[base+v]>>8], 1);
  __syncthreads();
  for(int i=t;i<NB;i+=256) if(h[i]) atomicAdd(&bcount[i], h[i]);
}

// ---------------- fused: LDS-staged bucket scatter (blocks 0..195) + packX + packW x3 ----------------
// pairs element: src(16b) | local_dst(8b)<<16 | bucket(8b)<<24
__global__ __launch_bounds__(256) void k_scatter_pack(const int* __restrict__ src, const int* __restrict__ dst,
      const int* __restrict__ bcount, int* __restrict__ bfill, unsigned* __restrict__ pairs,
      const float* __restrict__ x, unsigned short* __restrict__ H0,
      const float* __restrict__ Wn0, const float* __restrict__ Wr0, unsigned short* __restrict__ Bp0,
      const float* __restrict__ Wn1, const float* __restrict__ Wr1, unsigned short* __restrict__ Bp1,
      const float* __restrict__ Wn2, const float* __restrict__ Wr2, unsigned short* __restrict__ Bp2){
  __shared__ int h[NB], lbase[NB], gbase[NB], cur[NB];
  __shared__ int sc[256];
  __shared__ unsigned staged[SCHUNK];
  int blk = blockIdx.x, t = threadIdx.x;
  if(blk < NCHUNK){
    for(int i=t;i<NB;i+=256) h[i]=0;
    __syncthreads();
    int base = blk*SCHUNK;
    int n = min(SCHUNK, N_EDGES-base);
    for(int v=t; v<n; v+=256) atomicAdd(&h[dst[base+v]>>8], 1);
    __syncthreads();
    // exclusive scan of GLOBAL bcount -> bucket bases
    int bc = (t<NB)? bcount[t] : 0;
    sc[t]=bc; __syncthreads();
    for(int off=1;off<256;off<<=1){ int u=(t>=off)?sc[t-off]:0; __syncthreads(); sc[t]+=u; __syncthreads(); }
    int bb_t = sc[t]-bc;
    __syncthreads();
    // exclusive scan of LOCAL hist
    int hv = (t<NB)? h[t] : 0;
    sc[t]=hv; __syncthreads();
    for(int off=1;off<256;off<<=1){ int u=(t>=off)?sc[t-off]:0; __syncthreads(); sc[t]+=u; __syncthreads(); }
    if(t<NB){ lbase[t]=sc[t]-hv; cur[t]=0; if(hv) gbase[t] = bb_t + atomicAdd(&bfill[t], hv); }
    __syncthreads();
    for(int v=t; v<n; v+=256){
      int s = src[base+v], d = dst[base+v];
      int b = d>>8;
      int rr = atomicAdd(&cur[b], 1);
      staged[lbase[b]+rr] = (unsigned)s | ((unsigned)(d&255)<<16) | ((unsigned)b<<24);
    }
    __syncthreads();
    for(int i=t; i<n; i+=256){
      unsigned p = staged[i];
      int b = (int)(p>>24);
      pairs[gbase[b] + (i - lbase[b])] = p;
    }
  } else if(blk < NCHUNK+PX_BLKS){
    int tid = (blk-NCHUNK)*256 + t;        // N_NODES*8 units of 8 feats
    if(tid < N_NODES*8){
      int row = tid>>3, q = tid&7;
      float4 a = ((const float4*)x)[(size_t)row*16 + q*2];
      float4 b = ((const float4*)x)[(size_t)row*16 + q*2 + 1];
      uint4 o;
      o.x = fpack(a.x,a.y); o.y = fpack(a.z,a.w);
      o.z = fpack(b.x,b.y); o.w = fpack(b.z,b.w);
      ((uint4*)H0)[(size_t)row*8 + q] = o;
    }
  } else {
    const float *Wn, *Wr; unsigned short* Bp; int KH, base;
    if(blk < NCHUNK+PX_BLKS+W0_BLKS){ Wn=Wn0; Wr=Wr0; Bp=Bp0; KH=IN_DIM; base=NCHUNK+PX_BLKS; }
    else if(blk < NCHUNK+PX_BLKS+W0_BLKS+W1_BLKS){ Wn=Wn1; Wr=Wr1; Bp=Bp1; KH=HID; base=NCHUNK+PX_BLKS+W0_BLKS; }
    else { Wn=Wn2; Wr=Wr2; Bp=Bp2; KH=HID; base=NCHUNK+PX_BLKS+W0_BLKS+W1_BLKS; }
    int NKS = (2*KH)/32;
    int id = (blk-base)*256 + t;
    if(id < 8*NKS*64){
      int lane = id & 63;
      int ks = (id>>6) % NKS;
      int nt = (id>>6) / NKS;
      int quad = lane>>4, m = lane&15;
      int c = nt*16 + m;
      unsigned short v[8];
      #pragma unroll
      for(int j=0;j<8;j++){
        int k = ks*32 + quad*8 + j;
        float w = (k < KH) ? Wn[(size_t)k*HID + c] : Wr[(size_t)(k-KH)*HID + c];
        v[j] = f2bf(w);
      }
      uint4 o;
      o.x = ((unsigned)v[1]<<16)|v[0]; o.y = ((unsigned)v[3]<<16)|v[2];
      o.z = ((unsigned)v[5]<<16)|v[4]; o.w = ((unsigned)v[7]<<16)|v[6];
      ((uint4*)Bp)[id] = o;
    }
  }
}

// ---------------- per-bucket exact CSR (eidx as u16) ----------------
__global__ __launch_bounds__(1024) void k_csr(const unsigned* __restrict__ pairs, const int* __restrict__ bcount,
                int* __restrict__ rowptr, float* __restrict__ invdeg, unsigned short* __restrict__ eidx){
  __shared__ int cnt[BUCKET], cur[BUCKET], sc[BUCKET];
  __shared__ int bb[2];
  int t = threadIdx.x;
  int b = blockIdx.x;
  if(t==0){ bb[0]=0; bb[1]=0; }
  if(t<BUCKET) cnt[t]=0;
  __syncthreads();
  if(t<NB){
    int c = bcount[t];
    if(t<b)  atomicAdd(&bb[0], c);
    if(t<=b) atomicAdd(&bb[1], c);
  }
  __syncthreads();
  int e0 = bb[0], e1 = bb[1];
  int node0 = b*BUCKET;
  for(int i=e0+t; i<e1; i+=1024) atomicAdd(&cnt[(int)((pairs[i]>>16)&0xFF)], 1);
  __syncthreads();
  if(t<BUCKET) sc[t]=cnt[t];
  __syncthreads();
  for(int off=1;off<BUCKET;off<<=1){
    int u=0;
    if(t<BUCKET && t>=off) u=sc[t-off];
    __syncthreads();
    if(t<BUCKET) sc[t]+=u;
    __syncthreads();
  }
  if(t<BUCKET && node0+t < N_NODES){
    int pre = sc[t]-cnt[t] + e0;
    rowptr[node0+t] = pre;
    cur[t] = pre;
    invdeg[node0+t] = 1.0f/(float)max(cnt[t],1);
  }
  if(b==0 && t==0) rowptr[N_NODES] = N_EDGES;
  __syncthreads();
  for(int i=e0+t; i<e1; i+=1024){
    unsigned p = pairs[i];
    int pos = atomicAdd(&cur[(p>>16)&0xFF], 1);
    eidx[pos] = (unsigned short)(p & 0xFFFF);
  }
}

// ---------------- mean aggregation: one node per wave, unrolled gather ----------------
template<int KH>   // 64 or 128
__global__ __launch_bounds__(256) void k_agg(const unsigned short* __restrict__ H,
                      const unsigned short* __restrict__ eidx, const int* __restrict__ rowptr,
                      const float* __restrict__ invdeg, unsigned short* __restrict__ AGG){
  const int F8  = KH/8;    // 8 / 16 lanes per row
  const int RPI = 64/F8;   // 8 / 4 rows per wave-iter
  int wave = threadIdx.x >> 6;
  int lane = threadIdx.x & 63;
  int n = blockIdx.x*4 + wave;
  int b = rowptr[n], e = rowptr[n+1];
  int r = lane / F8, q = lane % F8;
  float acc[8] = {0,0,0,0,0,0,0,0};
  int i = b + r;
  // unroll x4: issue 4 independent row-loads per batch (same per-lane order as x1)
  for(; i + 3*RPI < e; i += 4*RPI){
    int s0 = eidx[i], s1 = eidx[i+RPI], s2 = eidx[i+2*RPI], s3 = eidx[i+3*RPI];
    uint4 u0 = *(const uint4*)(H + (size_t)s0*KH + q*8);
    uint4 u1 = *(const uint4*)(H + (size_t)s1*KH + q*8);
    uint4 u2 = *(const uint4*)(H + (size_t)s2*KH + q*8);
    uint4 u3 = *(const uint4*)(H + (size_t)s3*KH + q*8);
    acc8(acc,u0); acc8(acc,u1); acc8(acc,u2); acc8(acc,u3);
  }
  for(; i + RPI < e; i += 2*RPI){
    int s0 = eidx[i], s1 = eidx[i+RPI];
    uint4 u0 = *(const uint4*)(H + (size_t)s0*KH + q*8);
    uint4 u1 = *(const uint4*)(H + (size_t)s1*KH + q*8);
    acc8(acc,u0); acc8(acc,u1);
  }
  for(; i < e; i += RPI){
    int s0 = eidx[i];
    uint4 u0 = *(const uint4*)(H + (size_t)s0*KH + q*8);
    acc8(acc,u0);
  }
  #pragma unroll
  for(int off = F8; off < 64; off <<= 1){
    #pragma unroll
    for(int k=0;k<8;k++) acc[k] += __shfl_xor(acc[k], off, 64);
  }
  if(lane < F8){
    float id = invdeg[n];
    uint4 o;
    o.x = fpack(acc[0]*id, acc[1]*id); o.y = fpack(acc[2]*id, acc[3]*id);
    o.z = fpack(acc[4]*id, acc[5]*id); o.w = fpack(acc[6]*id, acc[7]*id);
    *(uint4*)(AGG + (size_t)n*KH + q*8) = o;
  }
}

// ---------------- MFMA GEMM, 2 M-tiles/wave: raw = [AGG|H] @ [Wn;Wr] + b ----------------
template<int KH>   // 64 or 128; K = 2*KH
__global__ __launch_bounds__(256) void k_gemm(const unsigned short* __restrict__ AGG,
                     const unsigned short* __restrict__ H,
                     const unsigned short* __restrict__ Bp, const float* __restrict__ bias,
                     unsigned short* __restrict__ raw,
                     float* __restrict__ psum, float* __restrict__ psq){
  const int NKS = (2*KH)/32;
  const int LKS = KH/32;
  int wave = threadIdx.x>>6, lane = threadIdx.x&63;
  int row0 = blockIdx.x*128 + wave*32;          // tile0: row0, tile1: row0+16
  if(row0 >= N_NODES) return;
  bool t1ok = (row0 + 16) < N_NODES;            // 50000%16==0: tiles all-or-nothing
  int m = lane&15, quad = lane>>4;
  const unsigned short* Arow0 = AGG + (size_t)(row0+m)*KH + quad*8;
  const unsigned short* Hrow0 = H   + (size_t)(row0+m)*KH + quad*8;
  const unsigned short* Arow1 = AGG + (size_t)(row0+16+m)*KH + quad*8;
  const unsigned short* Hrow1 = H   + (size_t)(row0+16+m)*KH + quad*8;
  f32x4 acc0[8], acc1[8];
  #pragma unroll
  for(int nt=0;nt<8;nt++){ acc0[nt] = (f32x4){0.f,0.f,0.f,0.f}; acc1[nt] = (f32x4){0.f,0.f,0.f,0.f}; }
  #pragma unroll 1
  for(int ks=0; ks<NKS; ks++){
    bf16x8 a0 = (ks < LKS) ? *(const bf16x8*)(Arow0 + ks*32)
                           : *(const bf16x8*)(Hrow0 + (ks-LKS)*32);
    bf16x8 a1 = a0;
    if(t1ok) a1 = (ks < LKS) ? *(const bf16x8*)(Arow1 + ks*32)
                             : *(const bf16x8*)(Hrow1 + (ks-LKS)*32);
    const unsigned short* bp = Bp + ((size_t)ks*64 + lane)*8;
    #pragma unroll
    for(int nt=0;nt<8;nt++){
      bf16x8 b = *(const bf16x8*)(bp + (size_t)nt*NKS*64*8);
      acc0[nt] = __builtin_amdgcn_mfma_f32_16x16x32_bf16(a0, b, acc0[nt], 0, 0, 0);
      acc1[nt] = __builtin_amdgcn_mfma_f32_16x16x32_bf16(a1, b, acc1[nt], 0, 0, 0);
    }
  }
  int sp = blockIdx.x & (SPREAD-1);
  #pragma unroll
  for(int nt=0;nt<8;nt++){
    int col = nt*16 + m;
    float bv = bias[col];
    float s = 0.f, s2 = 0.f;
    #pragma unroll
    for(int reg=0;reg<4;reg++){
      float v = acc0[nt][reg] + bv;
      int row = row0 + quad*4 + reg;
      raw[(size_t)row*HID + col] = f2bf(v);
      s += v; s2 += v*v;
    }
    if(t1ok){
      #pragma unroll
      for(int reg=0;reg<4;reg++){
        float v = acc1[nt][reg] + bv;
        int row = row0 + 16 + quad*4 + reg;
        raw[(size_t)row*HID + col] = f2bf(v);
        s += v; s2 += v*v;
      }
    }
    s  += __shfl_xor(s, 16, 64);  s  += __shfl_xor(s, 32, 64);
    s2 += __shfl_xor(s2, 16, 64); s2 += __shfl_xor(s2, 32, 64);
    if(quad==0){
      atomicAdd(&psum[sp*HID+col], s);
      atomicAdd(&psq [sp*HID+col], s2);
    }
  }
}

// ---------------- BN+ReLU transform (inline stats reduce): raw -> H_next ----------------
__global__ __launch_bounds__(256) void k_transform(const unsigned short* __restrict__ raw,
      const float* __restrict__ psum, const float* __restrict__ psq,
      const float* __restrict__ gamma, const float* __restrict__ beta,
      unsigned short* __restrict__ Hout){
  __shared__ float s_sc[HID], s_sf[HID];
  int t = threadIdx.x;
  if(t < HID){
    float s=0.f, s2=0.f;
    #pragma unroll
    for(int i=0;i<SPREAD;i++){ s += psum[i*HID+t]; s2 += psq[i*HID+t]; }
    float mu  = s  * (1.0f/(float)N_NODES);
    float var = s2 * (1.0f/(float)N_NODES) - mu*mu;
    float rstd = rsqrtf(var + BN_EPS);
    float sc = rstd * gamma[t];
    s_sc[t] = sc; s_sf[t] = beta[t] - mu*sc;
  }
  __syncthreads();
  int tid = blockIdx.x*256 + t;   // N_NODES*16 uint4 units
  if(tid >= N_NODES*16) return;
  int q = tid & 15;
  uint4 u = ((const uint4*)raw)[tid];
  float f0 = fmaxf(fmaf(bflo(u.x), s_sc[q*8+0], s_sf[q*8+0]), 0.f);
  float f1 = fmaxf(fmaf(bfhi(u.x), s_sc[q*8+1], s_sf[q*8+1]), 0.f);
  float f2 = fmaxf(fmaf(bflo(u.y), s_sc[q*8+2], s_sf[q*8+2]), 0.f);
  float f3 = fmaxf(fmaf(bfhi(u.y), s_sc[q*8+3], s_sf[q*8+3]), 0.f);
  float f4 = fmaxf(fmaf(bflo(u.z), s_sc[q*8+4], s_sf[q*8+4]), 0.f);
  float f5 = fmaxf(fmaf(bfhi(u.z), s_sc[q*8+5], s_sf[q*8+5]), 0.f);
  float f6 = fmaxf(fmaf(bflo(u.w), s_sc[q*8+6], s_sf[q*8+6]), 0.f);
  float f7 = fmaxf(fmaf(bfhi(u.w), s_sc[q*8+7], s_sf[q*8+7]), 0.f);
  uint4 o;
  o.x = fpack(f0,f1); o.y = fpack(f2,f3); o.z = fpack(f4,f5); o.w = fpack(f6,f7);
  ((uint4*)Hout)[tid] = o;
}

// ---------------- global mean pool (batch sorted; inline BN2 stats + ReLU) ----------------
__global__ __launch_bounds__(128) void k_pool(const unsigned short* __restrict__ raw, const int* __restrict__ batch,
                       const float* __restrict__ psum, const float* __restrict__ psq,
                       const float* __restrict__ gamma, const float* __restrict__ beta,
                       float* __restrict__ pooled, float* __restrict__ cnt){
  const int CH = 32;
  int f = threadIdx.x;
  float s=0.f, s2=0.f;
  #pragma unroll
  for(int i=0;i<SPREAD;i++){ s += psum[i*HID+f]; s2 += psq[i*HID+f]; }
  float mu  = s  * (1.0f/(float)N_NODES);
  float var = s2 * (1.0f/(float)N_NODES) - mu*mu;
  float rstd = rsqrtf(var + BN_EPS);
  float sc = rstd * gamma[f];
  float sf = beta[f] - mu*sc;
  int n0 = blockIdx.x * CH;
  int nEnd = min(n0+CH, N_NODES);
  float acc = 0.f; int curg = -1; int c = 0;
  for(int n=n0;n<nEnd;n++){
    int b = batch[n];
    if(b != curg){
      if(curg >= 0){
        atomicAdd(&pooled[curg*HID+f], acc);
        if(f==0) atomicAdd(&cnt[curg], (float)c);
      }
      acc = 0.f; c = 0; curg = b;
    }
    float v = bf2f(raw[(size_t)n*HID + f]);
    acc += fmaxf(fmaf(v, sc, sf), 0.f);
    c++;
  }
  if(curg >= 0){
    atomicAdd(&pooled[curg*HID+f], acc);
    if(f==0) atomicAdd(&cnt[curg], (float)c);
  }
}

// ---------------- MLP head: one wave per graph ----------------
__global__ void k_mlp(const float* __restrict__ pooled, const float* __restrict__ cnt,
                      const float* __restrict__ fc1W, const float* __restrict__ fc1b,
                      const float* __restrict__ fc2W, const float* __restrict__ fc2b,
                      float* __restrict__ out){
  __shared__ float p[HID];
  int g = blockIdx.x; int t = threadIdx.x;
  float ic = 1.0f / fmaxf(cnt[g], 1.0f);
  p[t]      = pooled[g*HID + t]      * ic;
  p[t + 64] = pooled[g*HID + t + 64] * ic;
  __syncthreads();
  float z = fc1b[t];
  #pragma unroll 4
  for(int k=0;k<HID;k++) z += p[k]*fc1W[k*64 + t];
  z = fmaxf(z, 0.f);
  float v = z * fc2W[t];
  #pragma unroll
  for(int off=32; off>0; off>>=1) v += __shfl_down(v, off, 64);
  if(t==0) out[g] = 1.0f/(1.0f + expf(-(v + fc2b[0])));
}

extern "C" void kernel_launch(void* const* d_in, const int* in_sizes, int n_in,
                              void* d_out, int out_size, void* d_ws, size_t ws_size,
                              hipStream_t stream){
  const float* x    = (const float*)d_in[0];
  const int*   ei   = (const int*)d_in[1];
  const int*   batch= (const int*)d_in[2];
  const float* Wn0=(const float*)d_in[3]; const float* Wr0=(const float*)d_in[4]; const float* b0=(const float*)d_in[5];
  const float* Wn1=(const float*)d_in[6]; const float* Wr1=(const float*)d_in[7]; const float* b1=(const float*)d_in[8];
  const float* Wn2=(const float*)d_in[9]; const float* Wr2=(const float*)d_in[10]; const float* b2=(const float*)d_in[11];
  const float* gamma=(const float*)d_in[12]; const float* beta=(const float*)d_in[13];
  const float* fc1W=(const float*)d_in[14]; const float* fc1b=(const float*)d_in[15];
  const float* fc2W=(const float*)d_in[16]; const float* fc2b=(const float*)d_in[17];
  float* out = (float*)d_out;

  char* ws = (char*)d_ws;
  size_t off = 0;
  auto alloc = [&](size_t bytes)->char*{ char* p = ws + off; off += (bytes + 255) & ~(size_t)255; return p; };

  // --- zeroed region (single memset): bcount | bfill | pstats | pooled+cnt ---
  char* zero0   = ws + off;
  int*   bcount = (int*)alloc((size_t)NB*4);
  int*   bfill  = (int*)alloc((size_t)NB*4);
  float* pstats = (float*)alloc((size_t)3*2*SPREAD*HID*4);
  float* pooled = (float*)alloc(((size_t)NUM_GRAPHS*HID + NUM_GRAPHS)*4);
  float* cnt    = pooled + (size_t)NUM_GRAPHS*HID;
  size_t zbytes = (size_t)((ws + off) - zero0);

  // --- non-zeroed scratch ---
  unsigned short* H0  = (unsigned short*)alloc((size_t)N_NODES*IN_DIM*2);
  unsigned short* H1  = (unsigned short*)alloc((size_t)N_NODES*HID*2);
  unsigned short* H2  = (unsigned short*)alloc((size_t)N_NODES*HID*2);
  unsigned short* AGG = (unsigned short*)alloc((size_t)N_NODES*HID*2);
  unsigned short* raw = (unsigned short*)alloc((size_t)N_NODES*HID*2);
  unsigned short* Bp0 = (unsigned short*)alloc((size_t)8*4*64*8*2);
  unsigned short* Bp1 = (unsigned short*)alloc((size_t)8*8*64*8*2);
  unsigned short* Bp2 = (unsigned short*)alloc((size_t)8*8*64*8*2);
  float* invdeg = (float*)alloc((size_t)N_NODES*4);
  int* rowptr   = (int*)alloc((size_t)(N_NODES+1)*4);
  unsigned short* eidx = (unsigned short*)alloc((size_t)N_EDGES*2);
  unsigned* pairs = (unsigned*)alloc((size_t)N_EDGES*4);

  auto psumL = [&](int l){ return pstats + (size_t)l*2*SPREAD*HID; };
  auto psqL  = [&](int l){ return pstats + (size_t)l*2*SPREAD*HID + (size_t)SPREAD*HID; };

  const int* src = ei;
  const int* dst = ei + N_EDGES;

  hipMemsetAsync(zero0, 0, zbytes, stream);

  // CSR build + packs (packs ride along with scatter dispatch)
  k_hist<<<NCHUNK, 256, 0, stream>>>(dst, bcount);
  k_scatter_pack<<<NCHUNK+PX_BLKS+W0_BLKS+2*W1_BLKS, 256, 0, stream>>>(src, dst, bcount, bfill, pairs,
      x, H0, Wn0, Wr0, Bp0, Wn1, Wr1, Bp1, Wn2, Wr2, Bp2);
  k_csr<<<NB, 1024, 0, stream>>>(pairs, bcount, rowptr, invdeg, eidx);

  const int GEMM_BLKS = (N_NODES + 127)/128;   // 391

  // ---- layer 0 ----
  k_agg<IN_DIM><<<N_NODES/4, 256, 0, stream>>>(H0, eidx, rowptr, invdeg, AGG);
  k_gemm<IN_DIM><<<GEMM_BLKS, 256, 0, stream>>>(AGG, H0, Bp0, b0, raw, psumL(0), psqL(0));
  k_transform<<<(N_NODES*16)/256, 256, 0, stream>>>(raw, psumL(0), psqL(0), gamma+0*HID, beta+0*HID, H1);
  // ---- layer 1 ----
  k_agg<HID><<<N_NODES/4, 256, 0, stream>>>(H1, eidx, rowptr, invdeg, AGG);
  k_gemm<HID><<<GEMM_BLKS, 256, 0, stream>>>(AGG, H1, Bp1, b1, raw, psumL(1), psqL(1));
  k_transform<<<(N_NODES*16)/256, 256, 0, stream>>>(raw, psumL(1), psqL(1), gamma+1*HID, beta+1*HID, H2);
  // ---- layer 2 ----
  k_agg<HID><<<N_NODES/4, 256, 0, stream>>>(H2, eidx, rowptr, invdeg, AGG);
  k_gemm<HID><<<GEMM_BLKS, 256, 0, stream>>>(AGG, H2, Bp2, b2, raw, psumL(2), psqL(2));

  // ---- pool (inline BN2 stats + ReLU) + MLP head ----
  k_pool<<<(N_NODES+31)/32, 128, 0, stream>>>(raw, batch, psumL(2), psqL(2), gamma+2*HID, beta+2*HID, pooled, cnt);
  k_mlp<<<NUM_GRAPHS, 64, 0, stream>>>(pooled, cnt, fc1W, fc1b, fc2W, fc2b, out);
}

// Round 9
// 311.716 us; speedup vs baseline: 1.0357x; 1.0357x over previous
//
#include <hip/hip_runtime.h>

#define N_NODES 50000
#define N_EDGES 800000
#define NUM_GRAPHS 256
#define HID 128
#define IN_DIM 64
#define BN_EPS 1e-5f
#define SPREAD 16
#define NB 196            // buckets: dst>>8
#define BUCKET 256        // nodes per bucket
#define SCHUNK 4096       // edges per scatter block
#define NCHUNK 196        // ceil(N_EDGES/SCHUNK)
#define PX_BLKS 1563      // ceil(N_NODES*8/256)
#define W0_BLKS 8         // 8*4*64/256
#define W1_BLKS 16        // 8*8*64/256

typedef __attribute__((ext_vector_type(8))) short bf16x8;
typedef __attribute__((ext_vector_type(4))) float f32x4;

// ---- bf16 helpers ----
__device__ __forceinline__ float bf2f(unsigned short u){ union{unsigned i;float f;}c; c.i=((unsigned)u)<<16; return c.f; }
__device__ __forceinline__ float bflo(unsigned w){ union{unsigned i;float f;}c; c.i=w<<16; return c.f; }
__device__ __forceinline__ float bfhi(unsigned w){ union{unsigned i;float f;}c; c.i=w&0xFFFF0000u; return c.f; }
__device__ __forceinline__ unsigned short f2bf(float f){ union{float f;unsigned i;}c; c.f=f; unsigned r=c.i+0x7FFF+((c.i>>16)&1); return (unsigned short)(r>>16); }
__device__ __forceinline__ unsigned fpack(float a, float b){
  union{float f;unsigned i;}ca,cb; ca.f=a; cb.f=b;
  unsigned ra=((ca.i+0x7FFF+((ca.i>>16)&1))>>16)&0xFFFFu;
  unsigned rb=(cb.i+0x7FFF+((cb.i>>16)&1))&0xFFFF0000u;
  return ra|rb;
}
__device__ __forceinline__ void acc8(float* a, uint4 u){
  a[0]+=bflo(u.x); a[1]+=bfhi(u.x); a[2]+=bflo(u.y); a[3]+=bfhi(u.y);
  a[4]+=bflo(u.z); a[5]+=bfhi(u.z); a[6]+=bflo(u.w); a[7]+=bfhi(u.w);
}

// ---------------- bucket histogram ----------------
__global__ __launch_bounds__(256) void k_hist(const int* __restrict__ dst, int* __restrict__ bcount){
  __shared__ int h[NB];
  int t = threadIdx.x;
  for(int i=t;i<NB;i+=256) h[i]=0;
  __syncthreads();
  int base = blockIdx.x*SCHUNK;
  int n = min(SCHUNK, N_EDGES-base);
  for(int v=t; v<n; v+=256) atomicAdd(&h[dst[base+v]>>8], 1);
  __syncthreads();
  for(int i=t;i<NB;i+=256) if(h[i]) atomicAdd(&bcount[i], h[i]);
}

// ---------------- fused: LDS-staged bucket scatter (blocks 0..195) + packX + packW x3 ----------------
// pairs element: src(16b) | local_dst(8b)<<16 | bucket(8b)<<24
__global__ __launch_bounds__(256) void k_scatter_pack(const int* __restrict__ src, const int* __restrict__ dst,
      const int* __restrict__ bcount, int* __restrict__ bfill, unsigned* __restrict__ pairs,
      const float* __restrict__ x, unsigned short* __restrict__ H0,
      const float* __restrict__ Wn0, const float* __restrict__ Wr0, unsigned short* __restrict__ Bp0,
      const float* __restrict__ Wn1, const float* __restrict__ Wr1, unsigned short* __restrict__ Bp1,
      const float* __restrict__ Wn2, const float* __restrict__ Wr2, unsigned short* __restrict__ Bp2){
  __shared__ int h[NB], lbase[NB], gbase[NB], cur[NB];
  __shared__ int sc[256];
  __shared__ unsigned staged[SCHUNK];
  int blk = blockIdx.x, t = threadIdx.x;
  if(blk < NCHUNK){
    for(int i=t;i<NB;i+=256) h[i]=0;
    __syncthreads();
    int base = blk*SCHUNK;
    int n = min(SCHUNK, N_EDGES-base);
    for(int v=t; v<n; v+=256) atomicAdd(&h[dst[base+v]>>8], 1);
    __syncthreads();
    // exclusive scan of GLOBAL bcount -> bucket bases
    int bc = (t<NB)? bcount[t] : 0;
    sc[t]=bc; __syncthreads();
    for(int off=1;off<256;off<<=1){ int u=(t>=off)?sc[t-off]:0; __syncthreads(); sc[t]+=u; __syncthreads(); }
    int bb_t = sc[t]-bc;
    __syncthreads();
    // exclusive scan of LOCAL hist
    int hv = (t<NB)? h[t] : 0;
    sc[t]=hv; __syncthreads();
    for(int off=1;off<256;off<<=1){ int u=(t>=off)?sc[t-off]:0; __syncthreads(); sc[t]+=u; __syncthreads(); }
    if(t<NB){ lbase[t]=sc[t]-hv; cur[t]=0; if(hv) gbase[t] = bb_t + atomicAdd(&bfill[t], hv); }
    __syncthreads();
    for(int v=t; v<n; v+=256){
      int s = src[base+v], d = dst[base+v];
      int b = d>>8;
      int rr = atomicAdd(&cur[b], 1);
      staged[lbase[b]+rr] = (unsigned)s | ((unsigned)(d&255)<<16) | ((unsigned)b<<24);
    }
    __syncthreads();
    for(int i=t; i<n; i+=256){
      unsigned p = staged[i];
      int b = (int)(p>>24);
      pairs[gbase[b] + (i - lbase[b])] = p;
    }
  } else if(blk < NCHUNK+PX_BLKS){
    int tid = (blk-NCHUNK)*256 + t;        // N_NODES*8 units of 8 feats
    if(tid < N_NODES*8){
      int row = tid>>3, q = tid&7;
      float4 a = ((const float4*)x)[(size_t)row*16 + q*2];
      float4 b = ((const float4*)x)[(size_t)row*16 + q*2 + 1];
      uint4 o;
      o.x = fpack(a.x,a.y); o.y = fpack(a.z,a.w);
      o.z = fpack(b.x,b.y); o.w = fpack(b.z,b.w);
      ((uint4*)H0)[(size_t)row*8 + q] = o;
    }
  } else {
    const float *Wn, *Wr; unsigned short* Bp; int KH, base;
    if(blk < NCHUNK+PX_BLKS+W0_BLKS){ Wn=Wn0; Wr=Wr0; Bp=Bp0; KH=IN_DIM; base=NCHUNK+PX_BLKS; }
    else if(blk < NCHUNK+PX_BLKS+W0_BLKS+W1_BLKS){ Wn=Wn1; Wr=Wr1; Bp=Bp1; KH=HID; base=NCHUNK+PX_BLKS+W0_BLKS; }
    else { Wn=Wn2; Wr=Wr2; Bp=Bp2; KH=HID; base=NCHUNK+PX_BLKS+W0_BLKS+W1_BLKS; }
    int NKS = (2*KH)/32;
    int id = (blk-base)*256 + t;
    if(id < 8*NKS*64){
      int lane = id & 63;
      int ks = (id>>6) % NKS;
      int nt = (id>>6) / NKS;
      int quad = lane>>4, m = lane&15;
      int c = nt*16 + m;
      unsigned short v[8];
      #pragma unroll
      for(int j=0;j<8;j++){
        int k = ks*32 + quad*8 + j;
        float w = (k < KH) ? Wn[(size_t)k*HID + c] : Wr[(size_t)(k-KH)*HID + c];
        v[j] = f2bf(w);
      }
      uint4 o;
      o.x = ((unsigned)v[1]<<16)|v[0]; o.y = ((unsigned)v[3]<<16)|v[2];
      o.z = ((unsigned)v[5]<<16)|v[4]; o.w = ((unsigned)v[7]<<16)|v[6];
      ((uint4*)Bp)[id] = o;
    }
  }
}

// ---------------- per-bucket exact CSR (eidx as u16) ----------------
__global__ __launch_bounds__(1024) void k_csr(const unsigned* __restrict__ pairs, const int* __restrict__ bcount,
                int* __restrict__ rowptr, float* __restrict__ invdeg, unsigned short* __restrict__ eidx){
  __shared__ int cnt[BUCKET], cur[BUCKET], sc[BUCKET];
  __shared__ int bb[2];
  int t = threadIdx.x;
  int b = blockIdx.x;
  if(t==0){ bb[0]=0; bb[1]=0; }
  if(t<BUCKET) cnt[t]=0;
  __syncthreads();
  if(t<NB){
    int c = bcount[t];
    if(t<b)  atomicAdd(&bb[0], c);
    if(t<=b) atomicAdd(&bb[1], c);
  }
  __syncthreads();
  int e0 = bb[0], e1 = bb[1];
  int node0 = b*BUCKET;
  for(int i=e0+t; i<e1; i+=1024) atomicAdd(&cnt[(int)((pairs[i]>>16)&0xFF)], 1);
  __syncthreads();
  if(t<BUCKET) sc[t]=cnt[t];
  __syncthreads();
  for(int off=1;off<BUCKET;off<<=1){
    int u=0;
    if(t<BUCKET && t>=off) u=sc[t-off];
    __syncthreads();
    if(t<BUCKET) sc[t]+=u;
    __syncthreads();
  }
  if(t<BUCKET && node0+t < N_NODES){
    int pre = sc[t]-cnt[t] + e0;
    rowptr[node0+t] = pre;
    cur[t] = pre;
    invdeg[node0+t] = 1.0f/(float)max(cnt[t],1);
  }
  if(b==0 && t==0) rowptr[N_NODES] = N_EDGES;
  __syncthreads();
  for(int i=e0+t; i<e1; i+=1024){
    unsigned p = pairs[i];
    int pos = atomicAdd(&cur[(p>>16)&0xFF], 1);
    eidx[pos] = (unsigned short)(p & 0xFFFF);
  }
}

// ---------------- mean aggregation: one node per wave, unrolled gather ----------------
template<int KH>   // 64 or 128
__global__ __launch_bounds__(256) void k_agg(const unsigned short* __restrict__ H,
                      const unsigned short* __restrict__ eidx, const int* __restrict__ rowptr,
                      const float* __restrict__ invdeg, unsigned short* __restrict__ AGG){
  const int F8  = KH/8;    // 8 / 16 lanes per row
  const int RPI = 64/F8;   // 8 / 4 rows per wave-iter
  int wave = threadIdx.x >> 6;
  int lane = threadIdx.x & 63;
  int n = blockIdx.x*4 + wave;
  int b = rowptr[n], e = rowptr[n+1];
  int r = lane / F8, q = lane % F8;
  float acc[8] = {0,0,0,0,0,0,0,0};
  int i = b + r;
  // unroll x4: issue 4 independent row-loads per batch (same per-lane order as x1)
  for(; i + 3*RPI < e; i += 4*RPI){
    int s0 = eidx[i], s1 = eidx[i+RPI], s2 = eidx[i+2*RPI], s3 = eidx[i+3*RPI];
    uint4 u0 = *(const uint4*)(H + (size_t)s0*KH + q*8);
    uint4 u1 = *(const uint4*)(H + (size_t)s1*KH + q*8);
    uint4 u2 = *(const uint4*)(H + (size_t)s2*KH + q*8);
    uint4 u3 = *(const uint4*)(H + (size_t)s3*KH + q*8);
    acc8(acc,u0); acc8(acc,u1); acc8(acc,u2); acc8(acc,u3);
  }
  for(; i + RPI < e; i += 2*RPI){
    int s0 = eidx[i], s1 = eidx[i+RPI];
    uint4 u0 = *(const uint4*)(H + (size_t)s0*KH + q*8);
    uint4 u1 = *(const uint4*)(H + (size_t)s1*KH + q*8);
    acc8(acc,u0); acc8(acc,u1);
  }
  for(; i < e; i += RPI){
    int s0 = eidx[i];
    uint4 u0 = *(const uint4*)(H + (size_t)s0*KH + q*8);
    acc8(acc,u0);
  }
  #pragma unroll
  for(int off = F8; off < 64; off <<= 1){
    #pragma unroll
    for(int k=0;k<8;k++) acc[k] += __shfl_xor(acc[k], off, 64);
  }
  if(lane < F8){
    float id = invdeg[n];
    uint4 o;
    o.x = fpack(acc[0]*id, acc[1]*id); o.y = fpack(acc[2]*id, acc[3]*id);
    o.z = fpack(acc[4]*id, acc[5]*id); o.w = fpack(acc[6]*id, acc[7]*id);
    *(uint4*)(AGG + (size_t)n*KH + q*8) = o;
  }
}

// ---------------- MFMA GEMM: raw = [AGG|H] @ [Wn;Wr] + b, col-stats epilogue ----------------
template<int KH>   // 64 or 128; K = 2*KH
__global__ __launch_bounds__(256) void k_gemm(const unsigned short* __restrict__ AGG,
                     const unsigned short* __restrict__ H,
                     const unsigned short* __restrict__ Bp, const float* __restrict__ bias,
                     unsigned short* __restrict__ raw,
                     float* __restrict__ psum, float* __restrict__ psq){
  const int NKS = (2*KH)/32;
  const int LKS = KH/32;
  int wave = threadIdx.x>>6, lane = threadIdx.x&63;
  int row0w = blockIdx.x*64 + wave*16;
  if(row0w >= N_NODES) return;
  int m = lane&15, quad = lane>>4;
  const unsigned short* Arow = AGG + (size_t)(row0w+m)*KH + quad*8;
  const unsigned short* Hrow = H   + (size_t)(row0w+m)*KH + quad*8;
  f32x4 acc[8];
  #pragma unroll
  for(int nt=0;nt<8;nt++) acc[nt] = (f32x4){0.f,0.f,0.f,0.f};
  #pragma unroll 1
  for(int ks=0; ks<NKS; ks++){
    bf16x8 a = (ks < LKS) ? *(const bf16x8*)(Arow + ks*32)
                          : *(const bf16x8*)(Hrow + (ks-LKS)*32);
    const unsigned short* bp = Bp + ((size_t)ks*64 + lane)*8;
    #pragma unroll
    for(int nt=0;nt<8;nt++){
      bf16x8 b = *(const bf16x8*)(bp + (size_t)nt*NKS*64*8);
      acc[nt] = __builtin_amdgcn_mfma_f32_16x16x32_bf16(a, b, acc[nt], 0, 0, 0);
    }
  }
  int sp = blockIdx.x & (SPREAD-1);
  #pragma unroll
  for(int nt=0;nt<8;nt++){
    int col = nt*16 + m;
    float bv = bias[col];
    float s = 0.f, s2 = 0.f;
    #pragma unroll
    for(int reg=0;reg<4;reg++){
      float v = acc[nt][reg] + bv;
      int row = row0w + quad*4 + reg;
      raw[(size_t)row*HID + col] = f2bf(v);
      s += v; s2 += v*v;
    }
    s  += __shfl_xor(s, 16, 64);  s  += __shfl_xor(s, 32, 64);
    s2 += __shfl_xor(s2, 16, 64); s2 += __shfl_xor(s2, 32, 64);
    if(quad==0){
      atomicAdd(&psum[sp*HID+col], s);
      atomicAdd(&psq [sp*HID+col], s2);
    }
  }
}

// ---------------- BN+ReLU transform (inline stats reduce): raw -> H_next ----------------
__global__ __launch_bounds__(256) void k_transform(const unsigned short* __restrict__ raw,
      const float* __restrict__ psum, const float* __restrict__ psq,
      const float* __restrict__ gamma, const float* __restrict__ beta,
      unsigned short* __restrict__ Hout){
  __shared__ float s_sc[HID], s_sf[HID];
  int t = threadIdx.x;
  if(t < HID){
    float s=0.f, s2=0.f;
    #pragma unroll
    for(int i=0;i<SPREAD;i++){ s += psum[i*HID+t]; s2 += psq[i*HID+t]; }
    float mu  = s  * (1.0f/(float)N_NODES);
    float var = s2 * (1.0f/(float)N_NODES) - mu*mu;
    float rstd = rsqrtf(var + BN_EPS);
    float sc = rstd * gamma[t];
    s_sc[t] = sc; s_sf[t] = beta[t] - mu*sc;
  }
  __syncthreads();
  int tid = blockIdx.x*256 + t;   // N_NODES*16 uint4 units
  if(tid >= N_NODES*16) return;
  int q = tid & 15;
  uint4 u = ((const uint4*)raw)[tid];
  float f0 = fmaxf(fmaf(bflo(u.x), s_sc[q*8+0], s_sf[q*8+0]), 0.f);
  float f1 = fmaxf(fmaf(bfhi(u.x), s_sc[q*8+1], s_sf[q*8+1]), 0.f);
  float f2 = fmaxf(fmaf(bflo(u.y), s_sc[q*8+2], s_sf[q*8+2]), 0.f);
  float f3 = fmaxf(fmaf(bfhi(u.y), s_sc[q*8+3], s_sf[q*8+3]), 0.f);
  float f4 = fmaxf(fmaf(bflo(u.z), s_sc[q*8+4], s_sf[q*8+4]), 0.f);
  float f5 = fmaxf(fmaf(bfhi(u.z), s_sc[q*8+5], s_sf[q*8+5]), 0.f);
  float f6 = fmaxf(fmaf(bflo(u.w), s_sc[q*8+6], s_sf[q*8+6]), 0.f);
  float f7 = fmaxf(fmaf(bfhi(u.w), s_sc[q*8+7], s_sf[q*8+7]), 0.f);
  uint4 o;
  o.x = fpack(f0,f1); o.y = fpack(f2,f3); o.z = fpack(f4,f5); o.w = fpack(f6,f7);
  ((uint4*)Hout)[tid] = o;
}

// ---------------- global mean pool (batch sorted; inline BN2 stats + ReLU) ----------------
__global__ __launch_bounds__(128) void k_pool(const unsigned short* __restrict__ raw, const int* __restrict__ batch,
                       const float* __restrict__ psum, const float* __restrict__ psq,
                       const float* __restrict__ gamma, const float* __restrict__ beta,
                       float* __restrict__ pooled, float* __restrict__ cnt){
  const int CH = 32;
  int f = threadIdx.x;
  float s=0.f, s2=0.f;
  #pragma unroll
  for(int i=0;i<SPREAD;i++){ s += psum[i*HID+f]; s2 += psq[i*HID+f]; }
  float mu  = s  * (1.0f/(float)N_NODES);
  float var = s2 * (1.0f/(float)N_NODES) - mu*mu;
  float rstd = rsqrtf(var + BN_EPS);
  float sc = rstd * gamma[f];
  float sf = beta[f] - mu*sc;
  int n0 = blockIdx.x * CH;
  int nEnd = min(n0+CH, N_NODES);
  float acc = 0.f; int curg = -1; int c = 0;
  for(int n=n0;n<nEnd;n++){
    int b = batch[n];
    if(b != curg){
      if(curg >= 0){
        atomicAdd(&pooled[curg*HID+f], acc);
        if(f==0) atomicAdd(&cnt[curg], (float)c);
      }
      acc = 0.f; c = 0; curg = b;
    }
    float v = bf2f(raw[(size_t)n*HID + f]);
    acc += fmaxf(fmaf(v, sc, sf), 0.f);
    c++;
  }
  if(curg >= 0){
    atomicAdd(&pooled[curg*HID+f], acc);
    if(f==0) atomicAdd(&cnt[curg], (float)c);
  }
}

// ---------------- MLP head: one wave per graph ----------------
__global__ void k_mlp(const float* __restrict__ pooled, const float* __restrict__ cnt,
                      const float* __restrict__ fc1W, const float* __restrict__ fc1b,
                      const float* __restrict__ fc2W, const float* __restrict__ fc2b,
                      float* __restrict__ out){
  __shared__ float p[HID];
  int g = blockIdx.x; int t = threadIdx.x;
  float ic = 1.0f / fmaxf(cnt[g], 1.0f);
  p[t]      = pooled[g*HID + t]      * ic;
  p[t + 64] = pooled[g*HID + t + 64] * ic;
  __syncthreads();
  float z = fc1b[t];
  #pragma unroll 4
  for(int k=0;k<HID;k++) z += p[k]*fc1W[k*64 + t];
  z = fmaxf(z, 0.f);
  float v = z * fc2W[t];
  #pragma unroll
  for(int off=32; off>0; off>>=1) v += __shfl_down(v, off, 64);
  if(t==0) out[g] = 1.0f/(1.0f + expf(-(v + fc2b[0])));
}

extern "C" void kernel_launch(void* const* d_in, const int* in_sizes, int n_in,
                              void* d_out, int out_size, void* d_ws, size_t ws_size,
                              hipStream_t stream){
  const float* x    = (const float*)d_in[0];
  const int*   ei   = (const int*)d_in[1];
  const int*   batch= (const int*)d_in[2];
  const float* Wn0=(const float*)d_in[3]; const float* Wr0=(const float*)d_in[4]; const float* b0=(const float*)d_in[5];
  const float* Wn1=(const float*)d_in[6]; const float* Wr1=(const float*)d_in[7]; const float* b1=(const float*)d_in[8];
  const float* Wn2=(const float*)d_in[9]; const float* Wr2=(const float*)d_in[10]; const float* b2=(const float*)d_in[11];
  const float* gamma=(const float*)d_in[12]; const float* beta=(const float*)d_in[13];
  const float* fc1W=(const float*)d_in[14]; const float* fc1b=(const float*)d_in[15];
  const float* fc2W=(const float*)d_in[16]; const float* fc2b=(const float*)d_in[17];
  float* out = (float*)d_out;

  char* ws = (char*)d_ws;
  size_t off = 0;
  auto alloc = [&](size_t bytes)->char*{ char* p = ws + off; off += (bytes + 255) & ~(size_t)255; return p; };

  // --- zeroed region (single memset): bcount | bfill | pstats | pooled+cnt ---
  char* zero0   = ws + off;
  int*   bcount = (int*)alloc((size_t)NB*4);
  int*   bfill  = (int*)alloc((size_t)NB*4);
  float* pstats = (float*)alloc((size_t)3*2*SPREAD*HID*4);
  float* pooled = (float*)alloc(((size_t)NUM_GRAPHS*HID + NUM_GRAPHS)*4);
  float* cnt    = pooled + (size_t)NUM_GRAPHS*HID;
  size_t zbytes = (size_t)((ws + off) - zero0);

  // --- non-zeroed scratch ---
  unsigned short* H0  = (unsigned short*)alloc((size_t)N_NODES*IN_DIM*2);
  unsigned short* H1  = (unsigned short*)alloc((size_t)N_NODES*HID*2);
  unsigned short* H2  = (unsigned short*)alloc((size_t)N_NODES*HID*2);
  unsigned short* AGG = (unsigned short*)alloc((size_t)N_NODES*HID*2);
  unsigned short* raw = (unsigned short*)alloc((size_t)N_NODES*HID*2);
  unsigned short* Bp0 = (unsigned short*)alloc((size_t)8*4*64*8*2);
  unsigned short* Bp1 = (unsigned short*)alloc((size_t)8*8*64*8*2);
  unsigned short* Bp2 = (unsigned short*)alloc((size_t)8*8*64*8*2);
  float* invdeg = (float*)alloc((size_t)N_NODES*4);
  int* rowptr   = (int*)alloc((size_t)(N_NODES+1)*4);
  unsigned short* eidx = (unsigned short*)alloc((size_t)N_EDGES*2);
  unsigned* pairs = (unsigned*)alloc((size_t)N_EDGES*4);

  auto psumL = [&](int l){ return pstats + (size_t)l*2*SPREAD*HID; };
  auto psqL  = [&](int l){ return pstats + (size_t)l*2*SPREAD*HID + (size_t)SPREAD*HID; };

  const int* src = ei;
  const int* dst = ei + N_EDGES;

  hipMemsetAsync(zero0, 0, zbytes, stream);

  // CSR build + packs (packs ride along with scatter dispatch)
  k_hist<<<NCHUNK, 256, 0, stream>>>(dst, bcount);
  k_scatter_pack<<<NCHUNK+PX_BLKS+W0_BLKS+2*W1_BLKS, 256, 0, stream>>>(src, dst, bcount, bfill, pairs,
      x, H0, Wn0, Wr0, Bp0, Wn1, Wr1, Bp1, Wn2, Wr2, Bp2);
  k_csr<<<NB, 1024, 0, stream>>>(pairs, bcount, rowptr, invdeg, eidx);

  const int GEMM_BLKS = (N_NODES + 63)/64;   // 782

  // ---- layer 0 ----
  k_agg<IN_DIM><<<N_NODES/4, 256, 0, stream>>>(H0, eidx, rowptr, invdeg, AGG);
  k_gemm<IN_DIM><<<GEMM_BLKS, 256, 0, stream>>>(AGG, H0, Bp0, b0, raw, psumL(0), psqL(0));
  k_transform<<<(N_NODES*16)/256, 256, 0, stream>>>(raw, psumL(0), psqL(0), gamma+0*HID, beta+0*HID, H1);
  // ---- layer 1 ----
  k_agg<HID><<<N_NODES/4, 256, 0, stream>>>(H1, eidx, rowptr, invdeg, AGG);
  k_gemm<HID><<<GEMM_BLKS, 256, 0, stream>>>(AGG, H1, Bp1, b1, raw, psumL(1), psqL(1));
  k_transform<<<(N_NODES*16)/256, 256, 0, stream>>>(raw, psumL(1), psqL(1), gamma+1*HID, beta+1*HID, H2);
  // ---- layer 2 ----
  k_agg<HID><<<N_NODES/4, 256, 0, stream>>>(H2, eidx, rowptr, invdeg, AGG);
  k_gemm<HID><<<GEMM_BLKS, 256, 0, stream>>>(AGG, H2, Bp2, b2, raw, psumL(2), psqL(2));

  // ---- pool (inline BN2 stats + ReLU) + MLP head ----
  k_pool<<<(N_NODES+31)/32, 128, 0, stream>>>(raw, batch, psumL(2), psqL(2), gamma+2*HID, beta+2*HID, pooled, cnt);
  k_mlp<<<NUM_GRAPHS, 64, 0, stream>>>(pooled, cnt, fc1W, fc1b, fc2W, fc2b, out);
}